// Round 1
// baseline (632.289 us; speedup 1.0000x reference)
//
#include <hip/hip_runtime.h>
#include <stdint.h>

// Problem constants
#define B_ 4
#define N_ 4096
#define D_ 256
#define M_ (B_*N_)   // 16384

typedef _Float16 f16;
typedef _Float16 f16x8 __attribute__((ext_vector_type(8)));
typedef float    f32x4  __attribute__((ext_vector_type(4)));
typedef float    f32x16 __attribute__((ext_vector_type(16)));

#define MFMA16(A,B,C) __builtin_amdgcn_mfma_f32_16x16x32_f16(A,B,C,0,0,0)
#define MFMA32(A,B,C) __builtin_amdgcn_mfma_f32_32x32x16_f16(A,B,C,0,0,0)

// workspace layout (bytes)
#define QH_OFF   0u            // Qh:   16384*256*2 = 8388608  (PRE-SCALED by log2e, R10)
#define KH_OFF   8388608u      // Kh:   8388608 (PRE-SWIZZLED)
#define VT_OFF   16777216u     // Vt:   [4][256][4096] f16 = 8388608
#define WFCH_OFF 25165824u     // Wfch: 131072 (DMA image, 8 slabs x 16KB)
#define WQS_OFF  25296896u     // Wqs:  262144 (DMA image, hi|lo per dc-slab)
#define WKS_OFF  25559040u
#define WVS_OFF  25821184u
#define OP_OFF   26083328u     // Opart: f16 [4][16384][256] = 33554432
#define ML_OFF   59637760u     // Ml: f32 [4][16384][2] = 524288 (mo in log2 domain, R10)

typedef __attribute__((address_space(3))) uint32_t lds_u32;
typedef __attribute__((address_space(1))) const uint32_t g_u32;

__device__ __forceinline__ void stage16(const f16* g, f16* lbase) {
    __builtin_amdgcn_global_load_lds((g_u32*)g, (lds_u32*)lbase, 16, 0, 0);
}
__device__ __forceinline__ uint32_t pk2(float a, float b) {
    union { f16 h[2]; uint32_t u; } x;
    x.h[0] = (f16)a; x.h[1] = (f16)b;
    return x.u;
}
__device__ __forceinline__ float exp2_fast(float x) {
#if __has_builtin(__builtin_amdgcn_exp2f)
    return __builtin_amdgcn_exp2f(x);   // bare v_exp_f32
#else
    return exp2f(x);
#endif
}

// ---------------------------------------------------------------------------
// Kernel 1: weight conversion (unchanged from R9).
// ---------------------------------------------------------------------------
__global__ __launch_bounds__(256) void cvt_w(
    const float* __restrict__ Wq, const float* __restrict__ Wk,
    const float* __restrict__ Wv, const float* __restrict__ Wfc,
    f16* __restrict__ Wqs, f16* __restrict__ Wks, f16* __restrict__ Wvs,
    f16* __restrict__ Wfch)
{
    const int z = blockIdx.y;
    const float* W = (z==0) ? Wq : (z==1) ? Wk : (z==2) ? Wv : Wfc;
    int idx = (blockIdx.x * 256 + threadIdx.x) * 4;
    float4 v = *(const float4*)(W + idx);
    union { ushort4 u4; f16 h[4]; } hi, lo;
    float vv[4] = {v.x, v.y, v.z, v.w};
    #pragma unroll
    for (int j = 0; j < 4; j++) {
        hi.h[j] = (f16)vv[j];
        lo.h[j] = (f16)(vv[j] - (float)hi.h[j]);
    }
    int col = idx >> 8, k = idx & 255;
    int dc = k >> 5, c8 = (k >> 3) & 3, j = k & 7;
    int p  = c8 ^ ((col >> 2) & 3);
    if (z == 3) {
        *(ushort4*)(Wfch + dc*8192 + col*32 + p*8 + j) = hi.u4;
    } else {
        f16* Ws = (z==0) ? Wqs : (z==1) ? Wks : Wvs;
        int base = dc*16384 + col*32 + p*8 + j;
        *(ushort4*)(Ws + base)        = hi.u4;
        *(ushort4*)(Ws + base + 8192) = lo.u4;
    }
}

// ---------------------------------------------------------------------------
// Kernel 2: QKV projection (f16 MFMA hi/lo), LDS-staged B.
// R10: Qh is written PRE-SCALED by log2(e) so attn's softmax runs in the
// exp2 domain (v_exp_f32 without the v_mul range conversion). Single f16
// rounding after the f32 multiply -> same error order as before.
// ---------------------------------------------------------------------------
__global__ __launch_bounds__(256, 2) void proj_kernel(
    const float* __restrict__ x,
    const f16* __restrict__ Wqs, const f16* __restrict__ Wks,
    const f16* __restrict__ Wvs,
    const float* __restrict__ bq, const float* __restrict__ bk,
    const float* __restrict__ bv,
    f16* __restrict__ Qh, f16* __restrict__ Kh, f16* __restrict__ Vt)
{
    const int z = blockIdx.y;
    const f16*   Ws   = (z==0) ? Wqs : (z==1) ? Wks : Wvs;
    const float* bias = (z==0) ? bq  : (z==1) ? bk  : bv;

    __shared__ __align__(16) f16 Bs[2][16384];   // 64KB dbuf; VTs union below

    const int tid  = threadIdx.x;
    const int w    = tid >> 6;
    const int lane = tid & 63;
    const int l15  = lane & 15;
    const int q4   = lane >> 4;
    const int m0   = blockIdx.x * 64 + w * 16;
    const int rowA = m0 + l15;
    const int sw   = (l15 >> 2) & 3;             // B read swizzle key

    int s8[8];
    #pragma unroll
    for (int i = 0; i < 8; i++) s8[i] = (tid + i*256) * 8;

    f32x4 acc[16];
    #pragma unroll
    for (int nt = 0; nt < 16; nt++) acc[nt] = (f32x4){0.f,0.f,0.f,0.f};

    // prologue: DMA slab 0, load x chunk 0
    #pragma unroll
    for (int i = 0; i < 8; i++) stage16(Ws + s8[i], &Bs[0][0] + s8[i]);
    const float* xp = x + (size_t)rowA * 256;
    float4 a0 = *(const float4*)(xp + q4*8);
    float4 a1 = *(const float4*)(xp + q4*8 + 4);

    for (int dc = 0; dc < 8; dc++) {
        const int cur = dc & 1;
        __syncthreads();                         // drains DMA(dc); prev reads done
        if (dc < 7) {                            // DMA slab dc+1
            const f16* src = Ws + (size_t)(dc+1)*16384;
            f16* dst = &Bs[cur ^ 1][0];
            #pragma unroll
            for (int i = 0; i < 8; i++) stage16(src + s8[i], dst + s8[i]);
        }
        float av[8] = {a0.x,a0.y,a0.z,a0.w,a1.x,a1.y,a1.z,a1.w};
        f16x8 ah, alo;
        #pragma unroll
        for (int j = 0; j < 8; j++) {
            ah[j]  = (f16)av[j];
            alo[j] = (f16)(av[j] - (float)ah[j]);
        }
        if (dc < 7) {                            // prefetch next x chunk
            a0 = *(const float4*)(xp + (dc+1)*32 + q4*8);
            a1 = *(const float4*)(xp + (dc+1)*32 + q4*8 + 4);
        }
        const f16* Bc = &Bs[cur][0];
        #pragma unroll
        for (int nt = 0; nt < 16; nt++) {
            const f16* bp = Bc + (nt*16 + l15)*32 + ((q4 ^ sw) << 3);
            f16x8 bh = *(const f16x8*)bp;
            f16x8 bl = *(const f16x8*)(bp + 8192);
            acc[nt] = MFMA16(ah,  bl, acc[nt]);
            acc[nt] = MFMA16(alo, bh, acc[nt]);
            acc[nt] = MFMA16(ah,  bh, acc[nt]);
        }
    }

    if (z == 0) {
        #pragma unroll
        for (int nt = 0; nt < 16; nt++) {
            float bb = bias[nt*16 + l15];
            #pragma unroll
            for (int r = 0; r < 4; r++)
                Qh[(size_t)(m0 + q4*4 + r)*256 + nt*16 + l15] =
                    (f16)((acc[nt][r] + bb) * 1.44269504088896f);   // R10: log2e
        }
    } else if (z == 1) {
        // swizzled Kh image for attn's DMA staging
        const int cbase = (l15 >> 3);
        const int j     = l15 & 7;
        #pragma unroll
        for (int nt = 0; nt < 16; nt++) {
            float bb = bias[nt*16 + l15];
            int c = nt*2 + cbase;
            #pragma unroll
            for (int r = 0; r < 4; r++) {
                int m = m0 + q4*4 + r;
                Kh[(size_t)m*256 + (size_t)((c ^ (m & 7)) << 3) + j] = (f16)(acc[nt][r] + bb);
            }
        }
    } else {
        // V: transpose through LDS (unions with Bs), coalesced b128 stores
        uint32_t* VTs = (uint32_t*)&Bs[0][0];
        const int bb_ = m0 >> 12;
        const int n0  = (blockIdx.x * 64) & 4095;
        const int mloc = w*16 + q4*4;
        const int mc   = mloc >> 3;
        __syncthreads();
        #pragma unroll
        for (int nt = 0; nt < 16; nt++) {
            int e = nt*16 + l15;
            float bv_ = bias[e];
            uint32_t w0 = pk2(acc[nt][0]+bv_, acc[nt][1]+bv_);
            uint32_t w1 = pk2(acc[nt][2]+bv_, acc[nt][3]+bv_);
            int base = e*36 + ((mc ^ (e & 7)) << 2) + ((q4*2) & 3);
            VTs[base]     = w0;
            VTs[base + 1] = w1;
        }
        __syncthreads();
        #pragma unroll
        for (int i = 0; i < 8; i++) {
            int e  = w*64 + i*8 + (lane >> 3);
            int nc = lane & 7;
            const f16* src = (const f16*)&VTs[e*36 + ((nc ^ (e & 7)) << 2)];
            f16x8 v = *(const f16x8*)src;
            *(f16x8*)(Vt + ((size_t)bb_*256 + e)*4096 + n0 + nc*8) = v;
        }
    }
}

// ---------------------------------------------------------------------------
// Kernel 3: flash attention, transposed compute with 32x32x16 MFMA.
// R10 restructure (T15-style 2-deep softmax pipeline):
//  - sa(t) is carried across the barrier (saA/saB ping-pong, static indexing);
//    exp2/ls-sum/P-pack/shuffles for tile t run inside tile t+1's S-MFMA
//    shadow (wave keeps issuing VALU while MFMAs execute) instead of sitting
//    serially between the MFMA burst and the barrier.
//  - exp2-domain softmax (Qh pre-scaled by log2e): bare v_exp_f32, no v_mul.
//  - tree-max (max3-fusable) for the tile max; only max+vote(+rare rescale)
//    remain on the per-iteration critical path.
//  - s_setprio(1) around the MFMA+shadow region (T5).
// Memory layout, DMA schedule, swizzles, epilogue: unchanged from R7/R8.
// ---------------------------------------------------------------------------
#define MARGIN2 12.0f    // log2-domain hysteresis margin: p <= 2^12 (f16-safe)

__device__ __forceinline__ void build_bp(const float* p, int half,
                                         f16x8& bp0, f16x8& bp1)
{
    #pragma unroll
    for (int kh = 0; kh < 2; kh++) {
        uint32_t lo0 = pk2(p[8*kh+0], p[8*kh+1]);
        uint32_t lo1 = pk2(p[8*kh+2], p[8*kh+3]);
        uint32_t hi0 = pk2(p[8*kh+4], p[8*kh+5]);
        uint32_t hi1 = pk2(p[8*kh+6], p[8*kh+7]);
        uint32_t s0 = half ? lo0 : hi0;
        uint32_t s1 = half ? lo1 : hi1;
        uint32_t r0 = __shfl_xor(s0, 32);
        uint32_t r1 = __shfl_xor(s1, 32);
        uint32_t k0 = half ? hi0 : lo0;
        uint32_t k1 = half ? hi1 : lo1;
        union { uint32_t u[4]; f16x8 v; } bb;
        bb.u[0] = half ? r0 : k0;
        bb.u[1] = half ? r1 : k1;
        bb.u[2] = half ? k0 : r0;
        bb.u[3] = half ? k1 : r1;
        if (kh == 0) bp0 = bb.v; else bp1 = bb.v;
    }
}

template<int CUR, bool FIRST, bool LAST>
__device__ __forceinline__ void attn_body(
    int it, f32x16& SA, const f32x16& SP, f32x16* Oa, const f16x8* qf,
    f16x8& bp0, f16x8& bp1, float& mo, float& ls,
    f16* __restrict__ Ks, f16* __restrict__ Vs,
    const f16* __restrict__ kg0, const f16* __restrict__ vg0,
    const int* kslot, const int* voff,
    int l31, int half, int vx, int lane)
{
    __syncthreads();                          // drains K(it), V(it-1) DMAs
    if (!LAST) {                              // DMA K(it+1)
        const f16* kg = kg0 + (size_t)(it+1) * 8192;
        f16* kl = Ks + (CUR ^ 1) * 8192;
        #pragma unroll
        for (int i = 0; i < 4; i++) stage16(kg + kslot[i], kl + kslot[i]);
    }
    {                                         // DMA V(it)
        const f16* vg = vg0 + it*32;
        f16* vl = Vs + CUR * 8192;
        #pragma unroll
        for (int i = 0; i < 4; i++) stage16(vg + voff[i], vl + kslot[i]);
    }

    const f16* krp = Ks + CUR*8192 + l31*256;
    #pragma unroll
    for (int r = 0; r < 16; r++) SA[r] = 0.f;

    float p[16];
    __builtin_amdgcn_s_setprio(1);
    // S(t) MFMAs with softmax(t-1) exps in their issue shadow
    #pragma unroll
    for (int st = 0; st < 16; st++) {
        f16x8 ka = *(const f16x8*)(krp + (((st*2 + half) ^ (lane & 7)) << 3));
        SA = MFMA32(ka, qf[st], SA);
        if (!FIRST) p[st] = exp2_fast(SP[st] - mo);
    }
    if (!FIRST) {
        // ls tree-sum + P-pack + cross-half shuffles: still in MFMA shadow
        float s0 = (p[0]+p[1]) + (p[2]+p[3]);
        float s1 = (p[4]+p[5]) + (p[6]+p[7]);
        float s2 = (p[8]+p[9]) + (p[10]+p[11]);
        float s3 = (p[12]+p[13]) + (p[14]+p[15]);
        ls += (s0+s1) + (s2+s3);
        build_bp(p, half, bp0, bp1);
        // PV(t-1)
        const f16* vpp = Vs + (CUR^1)*8192 + l31*32;
        #pragma unroll
        for (int t = 0; t < 8; t++) {
            #pragma unroll
            for (int kh = 0; kh < 2; kh++) {
                f16x8 va = *(const f16x8*)(vpp + t*1024 + (((half + kh*2) ^ vx) << 3));
                Oa[t] = MFMA32(va, kh ? bp1 : bp0, Oa[t]);
            }
        }
    }
    __builtin_amdgcn_s_setprio(0);

    // vote/rescale for S(t) — the only softmax work left on the critical path
    float t0 = fmaxf(fmaxf(SA[0],SA[1]),   fmaxf(SA[2],SA[3]));
    float t1 = fmaxf(fmaxf(SA[4],SA[5]),   fmaxf(SA[6],SA[7]));
    float t2 = fmaxf(fmaxf(SA[8],SA[9]),   fmaxf(SA[10],SA[11]));
    float t3 = fmaxf(fmaxf(SA[12],SA[13]), fmaxf(SA[14],SA[15]));
    float tm = fmaxf(fmaxf(t0,t1), fmaxf(t2,t3));
    if (__any(tm > mo + MARGIN2)) {
        float tmq = fmaxf(tm, __shfl_xor(tm, 32));
        float mn = fmaxf(mo, tmq);
        float al = exp2_fast(mo - mn);
        mo = mn; ls *= al;
        #pragma unroll
        for (int t = 0; t < 8; t++)
            #pragma unroll
            for (int r = 0; r < 16; r++) Oa[t][r] *= al;
    }
}

__global__ __launch_bounds__(256, 2) void attn_kernel(
    const f16* __restrict__ Qh, const f16* __restrict__ Kh,
    const f16* __restrict__ Vt,
    f16* __restrict__ Opart, float* __restrict__ Ml)
{
    __shared__ __align__(16) f16 SMEM[32768];     // Ks[2][8192] | Vs[2][8192]
    f16* Ks = SMEM;
    f16* Vs = SMEM + 16384;

    const int combo = blockIdx.x & 15;
    const int b   = combo >> 2;
    const int sp  = combo & 3;
    const int qt  = blockIdx.x >> 4;              // 0..31
    const int tid  = threadIdx.x;
    const int w    = tid >> 6;
    const int lane = tid & 63;
    const int l31  = lane & 31;                   // q column
    const int half = lane >> 5;
    const int qbase = qt * 128 + w * 32;          // wave's q-row base (incl. w)
    const int vx   = (l31 >> 2) & 3;              // V image swizzle key

    // Q as B-frags (16 steps of d): lane holds Q[q][8d]  (pre-scaled by log2e)
    f16x8 qf[16];
    {
        const f16* qp = Qh + ((size_t)(b*4096 + qbase + l31))*256 + half*8;
        #pragma unroll
        for (int st = 0; st < 16; st++) qf[st] = *(const f16x8*)(qp + st*16);
    }

    f32x16 Oa[8];                                 // O^T d-tiles (C-layout)
    #pragma unroll
    for (int t = 0; t < 8; t++)
        #pragma unroll
        for (int r = 0; r < 16; r++) Oa[t][r] = 0.f;
    float mo = -3e38f, ls = 0.f;                  // per-lane (q = l31), log2 dom.

    const f16* kg0 = Kh + ((size_t)(b*4096 + sp*1024)) * 256;   // swizzled
    const f16* vg0 = Vt + ((size_t)b*256) * 4096 + sp*1024;

    int kslot[4], voff[4];
    #pragma unroll
    for (int i = 0; i < 4; i++) {
        int s = tid + i*256;
        kslot[i] = s * 8;
        int d = s >> 2;
        int kc = (s & 3) ^ ((s >> 4) & 3);        // image: pos = kc ^ ((d>>2)&3)
        voff[i] = d * 4096 + kc * 8;
    }

    // prologue: DMA K(0)
    #pragma unroll
    for (int i = 0; i < 4; i++) stage16(kg0 + kslot[i], Ks + kslot[i]);

    f16x8 bp0, bp1;                               // carried P^T B-frags
    f32x16 saA, saB;                              // carried S tiles (ping-pong)
    #pragma unroll
    for (int r = 0; r < 16; r++) { saA[r] = 0.f; saB[r] = 0.f; }

    attn_body<0, true,  false>(0, saA, saB, Oa, qf, bp0, bp1, mo, ls,
                               Ks, Vs, kg0, vg0, kslot, voff, l31, half, vx, lane);
    for (int itp = 0; itp < 15; itp++) {
        attn_body<1, false, false>(2*itp+1, saB, saA, Oa, qf, bp0, bp1, mo, ls,
                                   Ks, Vs, kg0, vg0, kslot, voff, l31, half, vx, lane);
        attn_body<0, false, false>(2*itp+2, saA, saB, Oa, qf, bp0, bp1, mo, ls,
                                   Ks, Vs, kg0, vg0, kslot, voff, l31, half, vx, lane);
    }
    attn_body<1, false, true>(31, saB, saA, Oa, qf, bp0, bp1, mo, ls,
                              Ks, Vs, kg0, vg0, kslot, voff, l31, half, vx, lane);

    // final: drain V(31) DMA, softmax(31) + PV(31)
    __syncthreads();
    {
        float p[16];
        #pragma unroll
        for (int r = 0; r < 16; r++) p[r] = exp2_fast(saB[r] - mo);
        float s0 = (p[0]+p[1]) + (p[2]+p[3]);
        float s1 = (p[4]+p[5]) + (p[6]+p[7]);
        float s2 = (p[8]+p[9]) + (p[10]+p[11]);
        float s3 = (p[12]+p[13]) + (p[14]+p[15]);
        ls += (s0+s1) + (s2+s3);
        build_bp(p, half, bp0, bp1);
        const f16* vpp = Vs + 8192 + l31*32;      // V(31) in Vs[1]
        #pragma unroll
        for (int t = 0; t < 8; t++) {
            #pragma unroll
            for (int kh = 0; kh < 2; kh++) {
                f16x8 va = *(const f16x8*)(vpp + t*1024 + (((half + kh*2) ^ vx) << 3));
                Oa[t] = MFMA32(va, kh ? bp1 : bp0, Oa[t]);
            }
        }
    }
    __syncthreads();                              // all waves done with SMEM tiles

    // epilogue: l across half-pair, normalize, un-transpose via per-wave LDS
    float l = ls + __shfl_xor(ls, 32);
    float inv = 1.0f / l;
    f16* tb = SMEM + w * 8192;                    // 16KB per wave
    #pragma unroll
    for (int t = 0; t < 8; t++) {
        #pragma unroll
        for (int rp = 0; rp < 8; rp++) {
            int r0 = rp * 2;
            int d  = (r0 & 3) + 8*(r0 >> 2) + 4*half + t*32;
            int c  = d >> 3, j = d & 7;
            uint32_t wv = pk2(Oa[t][r0]*inv, Oa[t][r0+1]*inv);
            *(uint32_t*)(tb + l31*256 + ((c ^ (l31 & 7)) << 3) + (j & 6)) = wv;
        }
    }
    // coalesced read-back + global store (per-wave region, rows = qbase+q)
    f16* opb = Opart + ((size_t)sp*M_ + b*4096 + qbase) * 256;
    #pragma unroll
    for (int i = 0; i < 16; i++) {
        int q = (i & 3)*8 + (lane >> 3);
        int c = (i >> 2)*8 + (lane & 7);
        f16x8 v = *(const f16x8*)(tb + q*256 + ((c ^ (q & 7)) << 3));
        *(f16x8*)(opb + (size_t)q*256 + c*8) = v;
    }
    if (half == 0) {
        size_t mrow = (size_t)sp*M_ + b*4096 + qbase + l31;
        Ml[mrow*2]     = mo;
        Ml[mrow*2 + 1] = l;
    }
}

// ---------------------------------------------------------------------------
// Kernel 4: merge 4 normalized k-quarter partials + FC + bias.
// R10: partial-max merge moves to exp2 domain (Ml's mo is log2-domain now).
// ---------------------------------------------------------------------------
__global__ __launch_bounds__(256, 2) void merge_fc_kernel(
    const f16* __restrict__ Opart, const float* __restrict__ Ml,
    const f16* __restrict__ Wfci, const float* __restrict__ bfc,
    float* __restrict__ out)
{
    __shared__ __align__(16) f16 Bs[2][8192];    // 2 x 16KB slabs

    const int tid  = threadIdx.x;
    const int w    = tid >> 6;
    const int lane = tid & 63;
    const int l15  = lane & 15;
    const int q4   = lane >> 4;
    const int m0   = blockIdx.x * 64 + w * 16;
    const int rowA = m0 + l15;
    const int sw   = (l15 >> 2) & 3;             // B read swizzle key

    int s4[4];
    #pragma unroll
    for (int i = 0; i < 4; i++) s4[i] = (tid + i*256) * 8;

    float mv[4], lv[4];
    #pragma unroll
    for (int p = 0; p < 4; p++) {
        mv[p] = Ml[((size_t)p*M_ + rowA)*2];
        lv[p] = Ml[((size_t)p*M_ + rowA)*2 + 1];
    }
    float mm = fmaxf(fmaxf(mv[0], mv[1]), fmaxf(mv[2], mv[3]));
    float cw[4], den = 0.f;
    #pragma unroll
    for (int p = 0; p < 4; p++) { cw[p] = exp2_fast(mv[p] - mm) * lv[p]; den += cw[p]; }
    float invd = 1.0f / den;
    #pragma unroll
    for (int p = 0; p < 4; p++) cw[p] *= invd;

    // prologue: DMA slab 0, prefetch Opart frags for dc=0
    #pragma unroll
    for (int i = 0; i < 4; i++) stage16(Wfci + s4[i], &Bs[0][0] + s4[i]);
    const f16* opb = Opart + (size_t)rowA*256 + q4*8;
    f16x8 of[4];
    #pragma unroll
    for (int p = 0; p < 4; p++) of[p] = *(const f16x8*)(opb + (size_t)p*M_*256);

    f32x4 acc[16];
    #pragma unroll
    for (int nt = 0; nt < 16; nt++) acc[nt] = (f32x4){0.f,0.f,0.f,0.f};

    for (int dc = 0; dc < 8; dc++) {
        const int cur = dc & 1;
        __syncthreads();                         // drains DMA(dc); prev reads done
        if (dc < 7) {
            const f16* src = Wfci + (size_t)(dc+1)*8192;
            f16* dst = &Bs[cur ^ 1][0];
            #pragma unroll
            for (int i = 0; i < 4; i++) stage16(src + s4[i], dst + s4[i]);
        }
        // weighted merge of the 4 partials -> A-frag
        float v[8] = {};
        #pragma unroll
        for (int p = 0; p < 4; p++)
            #pragma unroll
            for (int j = 0; j < 8; j++) v[j] += cw[p] * (float)of[p][j];
        f16x8 af;
        #pragma unroll
        for (int j = 0; j < 8; j++) af[j] = (f16)v[j];
        if (dc < 7) {                            // prefetch next Opart frags
            #pragma unroll
            for (int p = 0; p < 4; p++)
                of[p] = *(const f16x8*)(opb + (size_t)p*M_*256 + (dc+1)*32);
        }
        const f16* Bc = &Bs[cur][0];
        #pragma unroll
        for (int nt = 0; nt < 16; nt++) {
            f16x8 bf = *(const f16x8*)(Bc + (nt*16 + l15)*32 + ((q4 ^ sw) << 3));
            acc[nt] = MFMA16(af, bf, acc[nt]);
        }
    }
    #pragma unroll
    for (int nt = 0; nt < 16; nt++) {
        float bias = bfc[nt*16 + l15];
        #pragma unroll
        for (int r = 0; r < 4; r++)
            out[(size_t)(m0 + q4*4 + r) * 256 + nt*16 + l15] = acc[nt][r] + bias;
    }
}

// ---------------------------------------------------------------------------
extern "C" void kernel_launch(void* const* d_in, const int* in_sizes, int n_in,
                              void* d_out, int out_size, void* d_ws, size_t ws_size,
                              hipStream_t stream)
{
    const float* x   = (const float*)d_in[0];
    const float* Wq  = (const float*)d_in[1];
    const float* bq  = (const float*)d_in[2];
    const float* Wk  = (const float*)d_in[3];
    const float* bk  = (const float*)d_in[4];
    const float* Wv  = (const float*)d_in[5];
    const float* bv  = (const float*)d_in[6];
    const float* Wfc = (const float*)d_in[7];
    const float* bfc = (const float*)d_in[8];
    float* out = (float*)d_out;

    char* ws = (char*)d_ws;
    f16*   Qh    = (f16*)(ws + QH_OFF);
    f16*   Kh    = (f16*)(ws + KH_OFF);
    f16*   Vt    = (f16*)(ws + VT_OFF);
    f16*   Wfch  = (f16*)(ws + WFCH_OFF);
    f16*   Wqs   = (f16*)(ws + WQS_OFF);
    f16*   Wks   = (f16*)(ws + WKS_OFF);
    f16*   Wvs   = (f16*)(ws + WVS_OFF);
    f16*   Opart = (f16*)(ws + OP_OFF);
    float* Ml    = (float*)(ws + ML_OFF);

    cvt_w<<<dim3(64, 4), 256, 0, stream>>>(Wq, Wk, Wv, Wfc, Wqs, Wks, Wvs, Wfch);
    proj_kernel<<<dim3(256, 3), 256, 0, stream>>>(x, Wqs, Wks, Wvs, bq, bk, bv, Qh, Kh, Vt);
    attn_kernel<<<512, 256, 0, stream>>>(Qh, Kh, Vt, Opart, Ml);
    merge_fc_kernel<<<256, 256, 0, stream>>>(Opart, Ml, Wfch, bfc, out);
}

// Round 2
// 208.455 us; speedup vs baseline: 3.0332x; 3.0332x over previous
//
#include <hip/hip_runtime.h>
#include <stdint.h>

// Problem constants
#define B_ 4
#define N_ 4096
#define D_ 256
#define M_ (B_*N_)   // 16384

typedef _Float16 f16;
typedef _Float16 f16x8 __attribute__((ext_vector_type(8)));
typedef float    f32x4  __attribute__((ext_vector_type(4)));
typedef float    f32x16 __attribute__((ext_vector_type(16)));

#define MFMA16(A,B,C) __builtin_amdgcn_mfma_f32_16x16x32_f16(A,B,C,0,0,0)
#define MFMA32(A,B,C) __builtin_amdgcn_mfma_f32_32x32x16_f16(A,B,C,0,0,0)

// workspace layout (bytes)
#define QH_OFF   0u            // Qh:   16384*256*2 = 8388608  (PRE-SCALED by log2e)
#define KH_OFF   8388608u      // Kh:   8388608 (PRE-SWIZZLED)
#define VT_OFF   16777216u     // Vt:   [4][256][4096] f16 = 8388608
#define WFCH_OFF 25165824u     // Wfch: 131072 (DMA image, 8 slabs x 16KB)
#define WQS_OFF  25296896u     // Wqs:  262144 (DMA image, hi|lo per dc-slab)
#define WKS_OFF  25559040u
#define WVS_OFF  25821184u
#define OP_OFF   26083328u     // Opart: f16 [4][16384][256] = 33554432
#define ML_OFF   59637760u     // Ml: f32 [4][16384][2] = 524288 (mo log2-domain)

typedef __attribute__((address_space(3))) uint32_t lds_u32;
typedef __attribute__((address_space(1))) const uint32_t g_u32;

__device__ __forceinline__ void stage16(const f16* g, f16* lbase) {
    __builtin_amdgcn_global_load_lds((g_u32*)g, (lds_u32*)lbase, 16, 0, 0);
}
__device__ __forceinline__ uint32_t pk2(float a, float b) {
    union { f16 h[2]; uint32_t u; } x;
    x.h[0] = (f16)a; x.h[1] = (f16)b;
    return x.u;
}
__device__ __forceinline__ float exp2_fast(float x) {
#if __has_builtin(__builtin_amdgcn_exp2f)
    return __builtin_amdgcn_exp2f(x);   // bare v_exp_f32
#else
    return exp2f(x);
#endif
}

// ---------------------------------------------------------------------------
// Kernel 1: weight conversion (unchanged from R9).
// ---------------------------------------------------------------------------
__global__ __launch_bounds__(256) void cvt_w(
    const float* __restrict__ Wq, const float* __restrict__ Wk,
    const float* __restrict__ Wv, const float* __restrict__ Wfc,
    f16* __restrict__ Wqs, f16* __restrict__ Wks, f16* __restrict__ Wvs,
    f16* __restrict__ Wfch)
{
    const int z = blockIdx.y;
    const float* W = (z==0) ? Wq : (z==1) ? Wk : (z==2) ? Wv : Wfc;
    int idx = (blockIdx.x * 256 + threadIdx.x) * 4;
    float4 v = *(const float4*)(W + idx);
    union { ushort4 u4; f16 h[4]; } hi, lo;
    float vv[4] = {v.x, v.y, v.z, v.w};
    #pragma unroll
    for (int j = 0; j < 4; j++) {
        hi.h[j] = (f16)vv[j];
        lo.h[j] = (f16)(vv[j] - (float)hi.h[j]);
    }
    int col = idx >> 8, k = idx & 255;
    int dc = k >> 5, c8 = (k >> 3) & 3, j = k & 7;
    int p  = c8 ^ ((col >> 2) & 3);
    if (z == 3) {
        *(ushort4*)(Wfch + dc*8192 + col*32 + p*8 + j) = hi.u4;
    } else {
        f16* Ws = (z==0) ? Wqs : (z==1) ? Wks : Wvs;
        int base = dc*16384 + col*32 + p*8 + j;
        *(ushort4*)(Ws + base)        = hi.u4;
        *(ushort4*)(Ws + base + 8192) = lo.u4;
    }
}

// ---------------------------------------------------------------------------
// Kernel 2: QKV projection (f16 MFMA hi/lo), LDS-staged B.
// Qh written PRE-SCALED by log2(e) so attn softmax runs in exp2 domain
// (bare v_exp_f32). Single f16 rounding after the f32 multiply.
// ---------------------------------------------------------------------------
__global__ __launch_bounds__(256, 2) void proj_kernel(
    const float* __restrict__ x,
    const f16* __restrict__ Wqs, const f16* __restrict__ Wks,
    const f16* __restrict__ Wvs,
    const float* __restrict__ bq, const float* __restrict__ bk,
    const float* __restrict__ bv,
    f16* __restrict__ Qh, f16* __restrict__ Kh, f16* __restrict__ Vt)
{
    const int z = blockIdx.y;
    const f16*   Ws   = (z==0) ? Wqs : (z==1) ? Wks : Wvs;
    const float* bias = (z==0) ? bq  : (z==1) ? bk  : bv;

    __shared__ __align__(16) f16 Bs[2][16384];   // 64KB dbuf; VTs union below

    const int tid  = threadIdx.x;
    const int w    = tid >> 6;
    const int lane = tid & 63;
    const int l15  = lane & 15;
    const int q4   = lane >> 4;
    const int m0   = blockIdx.x * 64 + w * 16;
    const int rowA = m0 + l15;
    const int sw   = (l15 >> 2) & 3;             // B read swizzle key

    int s8[8];
    #pragma unroll
    for (int i = 0; i < 8; i++) s8[i] = (tid + i*256) * 8;

    f32x4 acc[16];
    #pragma unroll
    for (int nt = 0; nt < 16; nt++) acc[nt] = (f32x4){0.f,0.f,0.f,0.f};

    // prologue: DMA slab 0, load x chunk 0
    #pragma unroll
    for (int i = 0; i < 8; i++) stage16(Ws + s8[i], &Bs[0][0] + s8[i]);
    const float* xp = x + (size_t)rowA * 256;
    float4 a0 = *(const float4*)(xp + q4*8);
    float4 a1 = *(const float4*)(xp + q4*8 + 4);

    for (int dc = 0; dc < 8; dc++) {
        const int cur = dc & 1;
        __syncthreads();                         // drains DMA(dc); prev reads done
        if (dc < 7) {                            // DMA slab dc+1
            const f16* src = Ws + (size_t)(dc+1)*16384;
            f16* dst = &Bs[cur ^ 1][0];
            #pragma unroll
            for (int i = 0; i < 8; i++) stage16(src + s8[i], dst + s8[i]);
        }
        float av[8] = {a0.x,a0.y,a0.z,a0.w,a1.x,a1.y,a1.z,a1.w};
        f16x8 ah, alo;
        #pragma unroll
        for (int j = 0; j < 8; j++) {
            ah[j]  = (f16)av[j];
            alo[j] = (f16)(av[j] - (float)ah[j]);
        }
        if (dc < 7) {                            // prefetch next x chunk
            a0 = *(const float4*)(xp + (dc+1)*32 + q4*8);
            a1 = *(const float4*)(xp + (dc+1)*32 + q4*8 + 4);
        }
        const f16* Bc = &Bs[cur][0];
        #pragma unroll
        for (int nt = 0; nt < 16; nt++) {
            const f16* bp = Bc + (nt*16 + l15)*32 + ((q4 ^ sw) << 3);
            f16x8 bh = *(const f16x8*)bp;
            f16x8 bl = *(const f16x8*)(bp + 8192);
            acc[nt] = MFMA16(ah,  bl, acc[nt]);
            acc[nt] = MFMA16(alo, bh, acc[nt]);
            acc[nt] = MFMA16(ah,  bh, acc[nt]);
        }
    }

    if (z == 0) {
        #pragma unroll
        for (int nt = 0; nt < 16; nt++) {
            float bb = bias[nt*16 + l15];
            #pragma unroll
            for (int r = 0; r < 4; r++)
                Qh[(size_t)(m0 + q4*4 + r)*256 + nt*16 + l15] =
                    (f16)((acc[nt][r] + bb) * 1.44269504088896f);   // log2e
        }
    } else if (z == 1) {
        // swizzled Kh image for attn's DMA staging
        const int cbase = (l15 >> 3);
        const int j     = l15 & 7;
        #pragma unroll
        for (int nt = 0; nt < 16; nt++) {
            float bb = bias[nt*16 + l15];
            int c = nt*2 + cbase;
            #pragma unroll
            for (int r = 0; r < 4; r++) {
                int m = m0 + q4*4 + r;
                Kh[(size_t)m*256 + (size_t)((c ^ (m & 7)) << 3) + j] = (f16)(acc[nt][r] + bb);
            }
        }
    } else {
        // V: transpose through LDS (unions with Bs), coalesced b128 stores
        uint32_t* VTs = (uint32_t*)&Bs[0][0];
        const int bb_ = m0 >> 12;
        const int n0  = (blockIdx.x * 64) & 4095;
        const int mloc = w*16 + q4*4;
        const int mc   = mloc >> 3;
        __syncthreads();
        #pragma unroll
        for (int nt = 0; nt < 16; nt++) {
            int e = nt*16 + l15;
            float bv_ = bias[e];
            uint32_t w0 = pk2(acc[nt][0]+bv_, acc[nt][1]+bv_);
            uint32_t w1 = pk2(acc[nt][2]+bv_, acc[nt][3]+bv_);
            int base = e*36 + ((mc ^ (e & 7)) << 2) + ((q4*2) & 3);
            VTs[base]     = w0;
            VTs[base + 1] = w1;
        }
        __syncthreads();
        #pragma unroll
        for (int i = 0; i < 8; i++) {
            int e  = w*64 + i*8 + (lane >> 3);
            int nc = lane & 7;
            const f16* src = (const f16*)&VTs[e*36 + ((nc ^ (e & 7)) << 2)];
            f16x8 v = *(const f16x8*)src;
            *(f16x8*)(Vt + ((size_t)bb_*256 + e)*4096 + n0 + nc*8) = v;
        }
    }
}

// ---------------------------------------------------------------------------
// Kernel 3: flash attention, TRANSPOSED compute with 32x32x16 MFMA.
// R11 = R9 structure EXACTLY (no carried S tile — R10's carried saA/saB
// pushed ~48 regs past the 2-waves/SIMD cap and spilled to scratch:
// FETCH 29.5MB -> 1.03GB). Only zero-register-cost changes kept:
//  - exp2-domain softmax (Qh pre-scaled by log2e): bare v_exp_f32.
//  - tree-max (max3-fusable) for the tile max.
//  - s_setprio(1) around the interleaved MFMA region (T5).
// ---------------------------------------------------------------------------
#define MARGIN2 12.0f    // log2-domain hysteresis margin: p <= 2^12 (f16-safe)
__global__ __launch_bounds__(256, 2) void attn_kernel(
    const f16* __restrict__ Qh, const f16* __restrict__ Kh,
    const f16* __restrict__ Vt,
    f16* __restrict__ Opart, float* __restrict__ Ml)
{
    __shared__ __align__(16) f16 SMEM[32768];     // Ks[2][8192] | Vs[2][8192]
    f16* Ks = SMEM;
    f16* Vs = SMEM + 16384;

    const int combo = blockIdx.x & 15;
    const int b   = combo >> 2;
    const int sp  = combo & 3;
    const int qt  = blockIdx.x >> 4;              // 0..31
    const int tid  = threadIdx.x;
    const int w    = tid >> 6;
    const int lane = tid & 63;
    const int l31  = lane & 31;                   // q column
    const int half = lane >> 5;
    const int qbase = qt * 128 + w * 32;          // wave's q-row base (incl. w)
    const int vx   = (l31 >> 2) & 3;              // V image swizzle key

    // Q as B-frags (16 steps of d): lane holds Q[q][8d]  (pre-scaled by log2e)
    f16x8 qf[16];
    {
        const f16* qp = Qh + ((size_t)(b*4096 + qbase + l31))*256 + half*8;
        #pragma unroll
        for (int st = 0; st < 16; st++) qf[st] = *(const f16x8*)(qp + st*16);
    }

    f32x16 Oa[8];                                 // O^T d-tiles (C-layout)
    #pragma unroll
    for (int t = 0; t < 8; t++)
        #pragma unroll
        for (int r = 0; r < 16; r++) Oa[t][r] = 0.f;
    float mo = -3e38f, ls = 0.f;                  // per-lane (q = l31), log2 dom.

    const f16* kg0 = Kh + ((size_t)(b*4096 + sp*1024)) * 256;   // swizzled
    const f16* vg0 = Vt + ((size_t)b*256) * 4096 + sp*1024;

    int kslot[4], voff[4];
    #pragma unroll
    for (int i = 0; i < 4; i++) {
        int s = tid + i*256;
        kslot[i] = s * 8;
        int d = s >> 2;
        int kc = (s & 3) ^ ((s >> 4) & 3);        // image: pos = kc ^ ((d>>2)&3)
        voff[i] = d * 4096 + kc * 8;
    }

    // prologue: DMA K(0)
    #pragma unroll
    for (int i = 0; i < 4; i++) stage16(kg0 + kslot[i], Ks + kslot[i]);

    f16x8 bp0, bp1;                               // carried P^T B-frags

    for (int it = 0; it < 32; it++) {
        const int cur = it & 1;
        __syncthreads();                          // drains K(t), V(t-1) DMAs
        if (it + 1 < 32) {
            const f16* kg = kg0 + (size_t)(it+1) * 8192;
            f16* kl = Ks + (cur ^ 1) * 8192;
            #pragma unroll
            for (int i = 0; i < 4; i++) stage16(kg + kslot[i], kl + kslot[i]);
        }
        {
            const f16* vg = vg0 + it*32;
            f16* vl = Vs + cur * 8192;
            #pragma unroll
            for (int i = 0; i < 4; i++) stage16(vg + voff[i], vl + kslot[i]);
        }

        // S^T(t) interleaved with PV(t-1): 32 MFMAs
        const f16* krp = Ks + cur*8192 + l31*256;
        const f16* vpp = Vs + (cur^1)*8192 + l31*32;
        f32x16 sa;
        #pragma unroll
        for (int r = 0; r < 16; r++) sa[r] = 0.f;
        __builtin_amdgcn_s_setprio(1);
        if (it > 0) {
            #pragma unroll
            for (int st = 0; st < 16; st++) {
                f16x8 ka = *(const f16x8*)(krp + (((st*2 + half) ^ (lane & 7)) << 3));
                sa = MFMA32(ka, qf[st], sa);
                int t = st >> 1, kh = st & 1;
                f16x8 va = *(const f16x8*)(vpp + t*1024 + (((half + kh*2) ^ vx) << 3));
                Oa[t] = MFMA32(va, kh ? bp1 : bp0, Oa[t]);
            }
        } else {
            #pragma unroll
            for (int st = 0; st < 16; st++) {
                f16x8 ka = *(const f16x8*)(krp + (((st*2 + half) ^ (lane & 7)) << 3));
                sa = MFMA32(ka, qf[st], sa);
            }
        }
        __builtin_amdgcn_s_setprio(0);

        // per-lane hysteresis softmax (q = lane col), log2 domain, tree max
        float t0 = fmaxf(fmaxf(sa[0],sa[1]),   fmaxf(sa[2],sa[3]));
        float t1 = fmaxf(fmaxf(sa[4],sa[5]),   fmaxf(sa[6],sa[7]));
        float t2 = fmaxf(fmaxf(sa[8],sa[9]),   fmaxf(sa[10],sa[11]));
        float t3 = fmaxf(fmaxf(sa[12],sa[13]), fmaxf(sa[14],sa[15]));
        float tm = fmaxf(fmaxf(t0,t1), fmaxf(t2,t3));
        if (__any(tm > mo + MARGIN2)) {
            float tmq = fmaxf(tm, __shfl_xor(tm, 32));
            float mn = fmaxf(mo, tmq);
            float al = exp2_fast(mo - mn);
            mo = mn; ls *= al;
            #pragma unroll
            for (int t = 0; t < 8; t++)
                #pragma unroll
                for (int r = 0; r < 16; r++) Oa[t][r] *= al;
        }
        float p[16];
        #pragma unroll
        for (int r = 0; r < 16; r++) { p[r] = exp2_fast(sa[r] - mo); ls += p[r]; }

        // build P^T B-frags: keys 16kh + [0..7](h=0) / [8..15](h=1)
        #pragma unroll
        for (int kh = 0; kh < 2; kh++) {
            uint32_t lo0 = pk2(p[8*kh+0], p[8*kh+1]);
            uint32_t lo1 = pk2(p[8*kh+2], p[8*kh+3]);
            uint32_t hi0 = pk2(p[8*kh+4], p[8*kh+5]);
            uint32_t hi1 = pk2(p[8*kh+6], p[8*kh+7]);
            uint32_t s0 = half ? lo0 : hi0;
            uint32_t s1 = half ? lo1 : hi1;
            uint32_t r0 = __shfl_xor(s0, 32);
            uint32_t r1 = __shfl_xor(s1, 32);
            uint32_t k0 = half ? hi0 : lo0;
            uint32_t k1 = half ? hi1 : lo1;
            union { uint32_t u[4]; f16x8 v; } bb;
            bb.u[0] = half ? r0 : k0;
            bb.u[1] = half ? r1 : k1;
            bb.u[2] = half ? k0 : r0;
            bb.u[3] = half ? k1 : r1;
            if (kh == 0) bp0 = bb.v; else bp1 = bb.v;
        }
    }

    // final PV(31): drain V(31) DMA, then consume
    __syncthreads();
    {
        const f16* vpp = Vs + 8192 + l31*32;      // V(31) in Vs[1]
        #pragma unroll
        for (int t = 0; t < 8; t++) {
            #pragma unroll
            for (int kh = 0; kh < 2; kh++) {
                f16x8 va = *(const f16x8*)(vpp + t*1024 + (((half + kh*2) ^ vx) << 3));
                Oa[t] = MFMA32(va, kh ? bp1 : bp0, Oa[t]);
            }
        }
    }
    __syncthreads();                              // all waves done with SMEM tiles

    // epilogue: l across half-pair, normalize, un-transpose via per-wave LDS
    float l = ls + __shfl_xor(ls, 32);
    float inv = 1.0f / l;
    f16* tb = SMEM + w * 8192;                    // 16KB per wave
    #pragma unroll
    for (int t = 0; t < 8; t++) {
        #pragma unroll
        for (int rp = 0; rp < 8; rp++) {
            int r0 = rp * 2;
            int d  = (r0 & 3) + 8*(r0 >> 2) + 4*half + t*32;
            int c  = d >> 3, j = d & 7;
            uint32_t wv = pk2(Oa[t][r0]*inv, Oa[t][r0+1]*inv);
            *(uint32_t*)(tb + l31*256 + ((c ^ (l31 & 7)) << 3) + (j & 6)) = wv;
        }
    }
    // coalesced read-back + global store (per-wave region, rows = qbase+q)
    f16* opb = Opart + ((size_t)sp*M_ + b*4096 + qbase) * 256;
    #pragma unroll
    for (int i = 0; i < 16; i++) {
        int q = (i & 3)*8 + (lane >> 3);
        int c = (i >> 2)*8 + (lane & 7);
        f16x8 v = *(const f16x8*)(tb + q*256 + ((c ^ (q & 7)) << 3));
        *(f16x8*)(opb + (size_t)q*256 + c*8) = v;
    }
    if (half == 0) {
        size_t mrow = (size_t)sp*M_ + b*4096 + qbase + l31;
        Ml[mrow*2]     = mo;
        Ml[mrow*2 + 1] = l;
    }
}

// ---------------------------------------------------------------------------
// Kernel 4: merge 4 normalized k-quarter partials + FC + bias.
// (exp2 domain for the partial-max merge — Ml's mo is log2-domain.)
// ---------------------------------------------------------------------------
__global__ __launch_bounds__(256, 2) void merge_fc_kernel(
    const f16* __restrict__ Opart, const float* __restrict__ Ml,
    const f16* __restrict__ Wfci, const float* __restrict__ bfc,
    float* __restrict__ out)
{
    __shared__ __align__(16) f16 Bs[2][8192];    // 2 x 16KB slabs

    const int tid  = threadIdx.x;
    const int w    = tid >> 6;
    const int lane = tid & 63;
    const int l15  = lane & 15;
    const int q4   = lane >> 4;
    const int m0   = blockIdx.x * 64 + w * 16;
    const int rowA = m0 + l15;
    const int sw   = (l15 >> 2) & 3;             // B read swizzle key

    int s4[4];
    #pragma unroll
    for (int i = 0; i < 4; i++) s4[i] = (tid + i*256) * 8;

    float mv[4], lv[4];
    #pragma unroll
    for (int p = 0; p < 4; p++) {
        mv[p] = Ml[((size_t)p*M_ + rowA)*2];
        lv[p] = Ml[((size_t)p*M_ + rowA)*2 + 1];
    }
    float mm = fmaxf(fmaxf(mv[0], mv[1]), fmaxf(mv[2], mv[3]));
    float cw[4], den = 0.f;
    #pragma unroll
    for (int p = 0; p < 4; p++) { cw[p] = exp2_fast(mv[p] - mm) * lv[p]; den += cw[p]; }
    float invd = 1.0f / den;
    #pragma unroll
    for (int p = 0; p < 4; p++) cw[p] *= invd;

    // prologue: DMA slab 0, prefetch Opart frags for dc=0
    #pragma unroll
    for (int i = 0; i < 4; i++) stage16(Wfci + s4[i], &Bs[0][0] + s4[i]);
    const f16* opb = Opart + (size_t)rowA*256 + q4*8;
    f16x8 of[4];
    #pragma unroll
    for (int p = 0; p < 4; p++) of[p] = *(const f16x8*)(opb + (size_t)p*M_*256);

    f32x4 acc[16];
    #pragma unroll
    for (int nt = 0; nt < 16; nt++) acc[nt] = (f32x4){0.f,0.f,0.f,0.f};

    for (int dc = 0; dc < 8; dc++) {
        const int cur = dc & 1;
        __syncthreads();                         // drains DMA(dc); prev reads done
        if (dc < 7) {
            const f16* src = Wfci + (size_t)(dc+1)*8192;
            f16* dst = &Bs[cur ^ 1][0];
            #pragma unroll
            for (int i = 0; i < 4; i++) stage16(src + s4[i], dst + s4[i]);
        }
        // weighted merge of the 4 partials -> A-frag
        float v[8] = {};
        #pragma unroll
        for (int p = 0; p < 4; p++)
            #pragma unroll
            for (int j = 0; j < 8; j++) v[j] += cw[p] * (float)of[p][j];
        f16x8 af;
        #pragma unroll
        for (int j = 0; j < 8; j++) af[j] = (f16)v[j];
        if (dc < 7) {                            // prefetch next Opart frags
            #pragma unroll
            for (int p = 0; p < 4; p++)
                of[p] = *(const f16x8*)(opb + (size_t)p*M_*256 + (dc+1)*32);
        }
        const f16* Bc = &Bs[cur][0];
        #pragma unroll
        for (int nt = 0; nt < 16; nt++) {
            f16x8 bf = *(const f16x8*)(Bc + (nt*16 + l15)*32 + ((q4 ^ sw) << 3));
            acc[nt] = MFMA16(af, bf, acc[nt]);
        }
    }
    #pragma unroll
    for (int nt = 0; nt < 16; nt++) {
        float bias = bfc[nt*16 + l15];
        #pragma unroll
        for (int r = 0; r < 4; r++)
            out[(size_t)(m0 + q4*4 + r) * 256 + nt*16 + l15] = acc[nt][r] + bias;
    }
}

// ---------------------------------------------------------------------------
extern "C" void kernel_launch(void* const* d_in, const int* in_sizes, int n_in,
                              void* d_out, int out_size, void* d_ws, size_t ws_size,
                              hipStream_t stream)
{
    const float* x   = (const float*)d_in[0];
    const float* Wq  = (const float*)d_in[1];
    const float* bq  = (const float*)d_in[2];
    const float* Wk  = (const float*)d_in[3];
    const float* bk  = (const float*)d_in[4];
    const float* Wv  = (const float*)d_in[5];
    const float* bv  = (const float*)d_in[6];
    const float* Wfc = (const float*)d_in[7];
    const float* bfc = (const float*)d_in[8];
    float* out = (float*)d_out;

    char* ws = (char*)d_ws;
    f16*   Qh    = (f16*)(ws + QH_OFF);
    f16*   Kh    = (f16*)(ws + KH_OFF);
    f16*   Vt    = (f16*)(ws + VT_OFF);
    f16*   Wfch  = (f16*)(ws + WFCH_OFF);
    f16*   Wqs   = (f16*)(ws + WQS_OFF);
    f16*   Wks   = (f16*)(ws + WKS_OFF);
    f16*   Wvs   = (f16*)(ws + WVS_OFF);
    f16*   Opart = (f16*)(ws + OP_OFF);
    float* Ml    = (float*)(ws + ML_OFF);

    cvt_w<<<dim3(64, 4), 256, 0, stream>>>(Wq, Wk, Wv, Wfc, Wqs, Wks, Wvs, Wfch);
    proj_kernel<<<dim3(256, 3), 256, 0, stream>>>(x, Wqs, Wks, Wvs, bq, bk, bv, Qh, Kh, Vt);
    attn_kernel<<<512, 256, 0, stream>>>(Qh, Kh, Vt, Opart, Ml);
    merge_fc_kernel<<<256, 256, 0, stream>>>(Opart, Ml, Wfch, bfc, out);
}